// Round 7
// baseline (6937.525 us; speedup 1.0000x reference)
//
#include <hip/hip_runtime.h>
#include <cstdint>

constexpr int BB = 128;   // batch
constexpr int SS = 512;   // source length
constexpr int DD = 512;   // hidden dim
constexpr int TT = 64;    // decode steps
constexpr int OO = 3;     // output dim

constexpr float C2LE = 2.8853900817779268f;  // 2*log2(e)

typedef __attribute__((ext_vector_type(8))) short bf16x8;
typedef __attribute__((ext_vector_type(4))) float f32x4;
typedef unsigned int u32x4 __attribute__((ext_vector_type(4)));

__device__ __forceinline__ float tanh_fast(float x) {
  float e = __expf(2.0f * x);
  return 1.0f - 2.0f / (e + 1.0f);
}
__device__ __forceinline__ float sigmoid_fast(float x) {
  return 1.0f / (1.0f + __expf(-x));
}
__device__ __forceinline__ unsigned short f2bf(float f) {
  uint32_t u = __float_as_uint(f);
  uint32_t r = (u + 0x7FFFu + ((u >> 16) & 1u)) >> 16;  // RNE
  return (unsigned short)r;
}
__device__ __forceinline__ float bf2f(unsigned short h) {
  return __uint_as_float((uint32_t)h << 16);
}
__device__ __forceinline__ float2 bfx2(uint32_t u) {
  float2 r;
  r.x = __uint_as_float(u << 16);
  r.y = __uint_as_float(u & 0xFFFF0000u);
  return r;
}
__device__ __forceinline__ float fexp2(float x) {
#if __has_builtin(__builtin_amdgcn_exp2f)
  return __builtin_amdgcn_exp2f(x);
#else
  return exp2f(x);
#endif
}
__device__ __forceinline__ float frcp(float x) {
#if __has_builtin(__builtin_amdgcn_rcpf)
  return __builtin_amdgcn_rcpf(x);
#else
  return 1.0f / x;
#endif
}

// LLC-coherent (agent-scope) accessors for cross-block exchange.
__device__ __forceinline__ void gstore(float* p, float v) {
  __hip_atomic_store(p, v, __ATOMIC_RELAXED, __HIP_MEMORY_SCOPE_AGENT);
}
__device__ __forceinline__ float gload(const float* p) {
  return __hip_atomic_load(p, __ATOMIC_RELAXED, __HIP_MEMORY_SCOPE_AGENT);
}

// Fence-free pair barrier: every wave drains its own stores (vmcnt), then one
// lane does a relaxed agent-scope arrive+spin on this pair's private 256-B line.
__device__ __forceinline__ void pair_barrier(unsigned int* cnt,
                                             unsigned int target) {
  asm volatile("s_waitcnt vmcnt(0)" ::: "memory");
  __syncthreads();
  if (threadIdx.x == 0) {
    __hip_atomic_fetch_add(cnt, 1u, __ATOMIC_RELAXED, __HIP_MEMORY_SCOPE_AGENT);
    while (__hip_atomic_load(cnt, __ATOMIC_RELAXED,
                             __HIP_MEMORY_SCOPE_AGENT) < target)
      __builtin_amdgcn_s_sleep(2);
  }
  __syncthreads();
}

// ---------------------------------------------------------------------------
// MFMA bf16 GEMM: Uk2 = bf16( C2LE * (e_bf @ Ua_bf^T + bu) )   [B*S x D]
// ---------------------------------------------------------------------------
__global__ __launch_bounds__(256) void gemm_uk_mfma(
    const unsigned short* __restrict__ A, const unsigned short* __restrict__ Bw,
    const float* __restrict__ bias, unsigned short* __restrict__ Uk) {
  __shared__ unsigned short Asb[128 * 40];
  __shared__ unsigned short Bsb[128 * 40];
  const int tid = threadIdx.x;
  const int m0 = blockIdx.y * 128, n0 = blockIdx.x * 128;
  const int w = tid >> 6, l = tid & 63;
  const int wr = w >> 1, wc = w & 1;
  const int lm = l & 15, kg = l >> 4;

  f32x4 acc[4][4] = {};

  for (int kc = 0; kc < 512; kc += 32) {
    uint4 av[2], bv[2];
#pragma unroll
    for (int p = 0; p < 2; ++p) {
      int u = tid + p * 256;
      int r = u >> 2, ko = (u & 3) * 8;
      av[p] = *(const uint4*)(A + (size_t)(m0 + r) * 512 + kc + ko);
      bv[p] = *(const uint4*)(Bw + (size_t)(n0 + r) * 512 + kc + ko);
    }
    __syncthreads();
#pragma unroll
    for (int p = 0; p < 2; ++p) {
      int u = tid + p * 256;
      int r = u >> 2, ko = (u & 3) * 8;
      *(uint4*)&Asb[r * 40 + ko] = av[p];
      *(uint4*)&Bsb[r * 40 + ko] = bv[p];
    }
    __syncthreads();
    bf16x8 af[4], bfr[4];
#pragma unroll
    for (int i = 0; i < 4; ++i) {
      af[i]  = *(const bf16x8*)&Asb[(wr * 64 + i * 16 + lm) * 40 + kg * 8];
      bfr[i] = *(const bf16x8*)&Bsb[(wc * 64 + i * 16 + lm) * 40 + kg * 8];
    }
#pragma unroll
    for (int i = 0; i < 4; ++i)
#pragma unroll
      for (int j = 0; j < 4; ++j)
        acc[i][j] = __builtin_amdgcn_mfma_f32_16x16x32_bf16(af[i], bfr[j],
                                                            acc[i][j], 0, 0, 0);
  }

  const int row_base = m0 + wr * 64;
  const int col_base = n0 + wc * 64;
#pragma unroll
  for (int j = 0; j < 4; ++j) {
    const int col = col_base + j * 16 + lm;
    const float bu = bias[col];
#pragma unroll
    for (int i = 0; i < 4; ++i) {
      const int r0 = row_base + i * 16 + kg * 4;
#pragma unroll
      for (int rr = 0; rr < 4; ++rr)
        Uk[(size_t)(r0 + rr) * 512 + col] = f2bf(C2LE * (acc[i][j][rr] + bu));
    }
  }
}

// fp32 -> bf16, 8 elems/thread
__global__ __launch_bounds__(256) void conv_bf(const float* __restrict__ in,
                                               unsigned short* __restrict__ outp) {
  size_t idx = ((size_t)blockIdx.x * 256 + threadIdx.x) * 8;
  const float4* p = (const float4*)(in + idx);
  float4 a = p[0], b = p[1];
  uint4 r;
  r.x = f2bf(a.x) | ((uint32_t)f2bf(a.y) << 16);
  r.y = f2bf(a.z) | ((uint32_t)f2bf(a.w) << 16);
  r.z = f2bf(b.x) | ((uint32_t)f2bf(b.y) << 16);
  r.w = f2bf(b.z) | ((uint32_t)f2bf(b.w) << 16);
  *(uint4*)(outp + idx) = r;
}

// Wq2[j][k] = bf16(C2LE * Wa[j][k])   (row-major, contiguous k)
__global__ void prep_wq2(const float* __restrict__ Wa,
                         unsigned short* __restrict__ Wq2) {
  int idx = blockIdx.x * 256 + threadIdx.x;  // j*512 + k
  Wq2[idx] = f2bf(C2LE * Wa[idx]);
}

// WihR[col][k] = bf16(W_ih[col][k]), col = gate*512+d  (row-major, contig k)
__global__ void prep_wihr(const float* __restrict__ W_ih,
                          unsigned short* __restrict__ WihR) {
  int idx = blockIdx.x * 256 + threadIdx.x;  // col*512 + k
  int col = idx >> 9, k = idx & 511;
  WihR[idx] = f2bf(W_ih[(size_t)col * (DD + OO) + k]);
}

// WhhR same, from W_hh (ld 512)
__global__ void prep_whhr(const float* __restrict__ Whh,
                          unsigned short* __restrict__ WhhR) {
  int idx = blockIdx.x * 256 + threadIdx.x;  // col*512 + k
  WhhR[idx] = f2bf(Whh[idx]);
}

__global__ void prep_bq(const float* __restrict__ ba, float* __restrict__ bq) {
  int j = blockIdx.x * 256 + threadIdx.x;  // 512
  bq[j] = C2LE * ba[j];
}

// ---------------------------------------------------------------------------
// Persistent pair decode: 256 blocks = (b, half) x 1024 threads, whole T-loop.
// 3 fence-free pair barriers per step. Cross-block data via agent-scope (LLC)
// loads/stores only. Weight GEMVs read row-major bf16 with uint4 loads
// (16 B/lane, 8x fewer VMEM insts than R6's k-major scalar loads).
// ---------------------------------------------------------------------------
__global__ __launch_bounds__(1024, 1) void decode_pairs(
    const unsigned short* __restrict__ Uk2, const unsigned short* __restrict__ e_bf,
    const unsigned short* __restrict__ Wq2, const unsigned short* __restrict__ WihR,
    const unsigned short* __restrict__ WhhR, const float* __restrict__ bq,
    const float* __restrict__ W_ih, const float* __restrict__ b_ih,
    const float* __restrict__ b_hh, const float* __restrict__ e_last,
    const float* __restrict__ target, const float* __restrict__ Va_w,
    const float* __restrict__ W_out, const float* __restrict__ b_out,
    float* __restrict__ ctxp, char* __restrict__ bars,
    float* __restrict__ out_d, float* __restrict__ out_hT,
    float* __restrict__ out_attn) {
  const int blk = blockIdx.x, tid = threadIdx.x;
  const int b = blk >> 1, half = blk & 1;
  char* bar_base = bars + (size_t)b * 256;
  unsigned int* cnt = (unsigned int*)bar_base;
  float* stat4 = (float*)(bar_base + 16);  // [m0, l0, m1, l1]
  unsigned int bc = 0;

  __shared__ float va_s[528];
  __shared__ float qv_s[528];
  __shared__ float h_s[512];
  __shared__ float pd_s[512];
  __shared__ float u_s[256];
  __shared__ float w_s[256];
  __shared__ float red_s[16];
  __shared__ float part[16 * 520];
  __shared__ float ctx_s[512];
  __shared__ float gis[768];
  __shared__ float ghs[768];

  // persistent per-thread preloads: x-weights + biases for owned (gate, d)
  float wxr0 = 0.f, wxr1 = 0.f, wxr2 = 0.f, bihr = 0.f, bhhr = 0.f;
  if (tid < 768) {
    const int gate = tid >> 8, dl = tid & 255;
    const int row = gate * 512 + half * 256 + dl;
    const float* wp = W_ih + (size_t)row * (DD + OO) + DD;
    wxr0 = wp[0]; wxr1 = wp[1]; wxr2 = wp[2];
    bihr = b_ih[row]; bhhr = b_hh[row];
  }
  if (tid < 512) va_s[(tid >> 7) * 132 + (tid & 127)] = Va_w[tid];
  __syncthreads();

  for (int t = 0; t < TT; ++t) {
    // ---------------- P1: load h, full q2 GEMV, scores, local softmax -----
    if (tid < 512) {
      h_s[tid] = (t == 0) ? e_last[(size_t)b * 512 + tid]
                          : gload(out_hT + (size_t)b * 512 + tid);
    }
    __syncthreads();
    {
      const int col = tid & 511, kb = tid >> 9;
      const unsigned short* wp = Wq2 + (size_t)col * 512 + kb * 256;
      const float* hb = &h_s[kb * 256];
      float acc = 0.f;
#pragma unroll 8
      for (int k0 = 0; k0 < 256; k0 += 8) {
        uint4 uw = *(const uint4*)(wp + k0);
        float4 hv0 = *(const float4*)&hb[k0];
        float4 hv1 = *(const float4*)&hb[k0 + 4];
        float2 w0 = bfx2(uw.x), w1 = bfx2(uw.y);
        float2 w2 = bfx2(uw.z), w3 = bfx2(uw.w);
        acc += hv0.x * w0.x + hv0.y * w0.y;
        acc += hv0.z * w1.x + hv0.w * w1.y;
        acc += hv1.x * w2.x + hv1.y * w2.y;
        acc += hv1.z * w3.x + hv1.w * w3.y;
      }
      if (kb) pd_s[col] = acc;
      __syncthreads();
      if (!kb) {
        float q = acc + pd_s[col] + bq[col];
        qv_s[(col >> 7) * 132 + (col & 127)] = q;
      }
      // out_d[t-1] on half-0 (h_s is h after step t-1), threads 512..703
      if (half == 0 && t > 0 && tid >= 512 && tid < 704) {
        const int o = (tid - 512) >> 6, ln = tid & 63;
        const float* wrow = W_out + (size_t)o * DD;
        float a = 0.f;
        for (int i = ln; i < DD; i += 64) a += h_s[i] * wrow[i];
#pragma unroll
        for (int off = 32; off; off >>= 1) a += __shfl_xor(a, off);
        if (ln == 0)
          out_d[((size_t)b * TT + (t - 1)) * OO + o] = a + b_out[o];
      }
    }
    __syncthreads();
    {  // scores for own 256 s: 4 threads/s x 128 d
      const int sl = tid >> 2, qp = tid & 3;
      const u32x4* up = (const u32x4*)(Uk2 +
          ((size_t)b * SS + half * 256 + sl) * DD + qp * 128);
      const float* qb = &qv_s[qp * 132];
      const float* vb = &va_s[qp * 132];
      float acc = 0.f;
#pragma unroll 4
      for (int j = 0; j < 16; ++j) {
        u32x4 u = __builtin_nontemporal_load(up + j);
        float4 q0 = *(const float4*)&qb[j * 8], q1 = *(const float4*)&qb[j * 8 + 4];
        float4 v0 = *(const float4*)&vb[j * 8], v1 = *(const float4*)&vb[j * 8 + 4];
        float2 e0 = bfx2(u[0]), e1 = bfx2(u[1]), e2 = bfx2(u[2]), e3 = bfx2(u[3]);
        acc += v0.x * frcp(1.f + fexp2(q0.x + e0.x));
        acc += v0.y * frcp(1.f + fexp2(q0.y + e0.y));
        acc += v0.z * frcp(1.f + fexp2(q0.z + e1.x));
        acc += v0.w * frcp(1.f + fexp2(q0.w + e1.y));
        acc += v1.x * frcp(1.f + fexp2(q1.x + e2.x));
        acc += v1.y * frcp(1.f + fexp2(q1.y + e2.y));
        acc += v1.z * frcp(1.f + fexp2(q1.z + e3.x));
        acc += v1.w * frcp(1.f + fexp2(q1.w + e3.y));
      }
      acc += __shfl_xor(acc, 1);
      acc += __shfl_xor(acc, 2);
      if (qp == 0) u_s[sl] = -2.f * acc;  // logit (up to +const)
    }
    __syncthreads();
    {  // local softmax stats over own 256
      const int w4 = tid >> 6;
      float y = (tid < 256) ? u_s[tid] : -3.0e38f;
      float m = y;
#pragma unroll
      for (int off = 32; off; off >>= 1) m = fmaxf(m, __shfl_xor(m, off));
      if (w4 < 4 && (tid & 63) == 0) red_s[w4] = m;
      __syncthreads();
      const float gm =
          fmaxf(fmaxf(red_s[0], red_s[1]), fmaxf(red_s[2], red_s[3]));
      float e = (tid < 256) ? __expf(y - gm) : 0.f;
      float sm = e;
#pragma unroll
      for (int off = 32; off; off >>= 1) sm += __shfl_xor(sm, off);
      if (w4 < 4 && (tid & 63) == 0) red_s[8 + w4] = sm;
      __syncthreads();
      if (tid < 256) u_s[tid] = e;
      if (tid == 0) {
        gstore(&stat4[half * 2], gm);
        gstore(&stat4[half * 2 + 1],
               red_s[8] + red_s[9] + red_s[10] + red_s[11]);
      }
    }
    pair_barrier(cnt, 2 * (++bc));

    // ---------------- P2: finalize softmax, attn out, ctx partial ---------
    if (tid == 0) {
      red_s[8] = gload(&stat4[0]);
      red_s[9] = gload(&stat4[1]);
      red_s[10] = gload(&stat4[2]);
      red_s[11] = gload(&stat4[3]);
    }
    __syncthreads();
    {
      const float m0 = red_s[8], l0 = red_s[9], m1 = red_s[10], l1 = red_s[11];
      const float M = fmaxf(m0, m1);
      const float invZ = frcp(l0 * __expf(m0 - M) + l1 * __expf(m1 - M));
      const float al = __expf((half ? m1 : m0) - M) * invZ;
      if (tid < 256) {
        float wv = u_s[tid] * al;
        w_s[tid] = wv;
        __builtin_nontemporal_store(
            wv, out_attn + ((size_t)b * TT + t) * SS + half * 256 + tid);
      }
    }
    __syncthreads();
    {  // ctx partial over own 256 s: 16 s-groups x 64 d-slots of 8
      const int dsl = tid & 63, sg = tid >> 6;
      const unsigned short* eb =
          e_bf + ((size_t)b * SS + half * 256 + sg * 16) * DD + dsl * 8;
      float a0 = 0.f, a1 = 0.f, a2 = 0.f, a3 = 0.f;
      float a4 = 0.f, a5 = 0.f, a6 = 0.f, a7 = 0.f;
#pragma unroll 4
      for (int si = 0; si < 16; ++si) {
        u32x4 u = __builtin_nontemporal_load((const u32x4*)(eb + (size_t)si * DD));
        float ws = w_s[sg * 16 + si];
        float2 p0 = bfx2(u[0]), p1 = bfx2(u[1]), p2 = bfx2(u[2]), p3 = bfx2(u[3]);
        a0 += ws * p0.x; a1 += ws * p0.y;
        a2 += ws * p1.x; a3 += ws * p1.y;
        a4 += ws * p2.x; a5 += ws * p2.y;
        a6 += ws * p3.x; a7 += ws * p3.y;
      }
      float* pr = &part[sg * 520 + dsl * 8];
      float4 lo = {a0, a1, a2, a3}, hi = {a4, a5, a6, a7};
      *(float4*)&pr[0] = lo;
      *(float4*)&pr[4] = hi;
    }
    __syncthreads();
    if (tid < 512) {
      float r = 0.f;
#pragma unroll
      for (int sg = 0; sg < 16; ++sg) r += part[sg * 520 + tid];
      gstore(&ctxp[((size_t)b * 2 + half) * 512 + tid], r);
    }
    pair_barrier(cnt, 2 * (++bc));

    // ---------------- P3: gi/gh GEMV (own d-half) + GRU -------------------
    if (tid < 512)
      ctx_s[tid] = gload(&ctxp[(size_t)b * 2 * 512 + tid]) +
                   gload(&ctxp[((size_t)b * 2 + 1) * 512 + tid]);
    __syncthreads();
    if (tid < 768) {
      const int gate = tid >> 8, dl = tid & 255;
      const int col = gate * 512 + half * 256 + dl;
      const unsigned short* wi = WihR + (size_t)col * 512;
      const unsigned short* wh = WhhR + (size_t)col * 512;
      float ai = 0.f, ah = 0.f;
#pragma unroll 8
      for (int k0 = 0; k0 < 512; k0 += 8) {
        uint4 uwi = *(const uint4*)(wi + k0);
        uint4 uwh = *(const uint4*)(wh + k0);
        float4 c0 = *(const float4*)&ctx_s[k0];
        float4 c1 = *(const float4*)&ctx_s[k0 + 4];
        float4 h0 = *(const float4*)&h_s[k0];
        float4 h1 = *(const float4*)&h_s[k0 + 4];
        float2 i0 = bfx2(uwi.x), i1 = bfx2(uwi.y);
        float2 i2 = bfx2(uwi.z), i3 = bfx2(uwi.w);
        float2 g0 = bfx2(uwh.x), g1 = bfx2(uwh.y);
        float2 g2 = bfx2(uwh.z), g3 = bfx2(uwh.w);
        ai += c0.x * i0.x + c0.y * i0.y;
        ah += h0.x * g0.x + h0.y * g0.y;
        ai += c0.z * i1.x + c0.w * i1.y;
        ah += h0.z * g1.x + h0.w * g1.y;
        ai += c1.x * i2.x + c1.y * i2.y;
        ah += h1.x * g2.x + h1.y * g2.y;
        ai += c1.z * i3.x + c1.w * i3.y;
        ah += h1.z * g3.x + h1.w * g3.y;
      }
      float x0 = 0.f, x1 = 0.f, x2 = 0.f;
      if (t > 0) {
        const float* xp = target + ((size_t)b * TT + (t - 1)) * OO;
        x0 = xp[0]; x1 = xp[1]; x2 = xp[2];
      }
      gis[tid] = ai + bihr + x0 * wxr0 + x1 * wxr1 + x2 * wxr2;
      ghs[tid] = ah + bhhr;
    }
    __syncthreads();
    if (tid < 256) {
      const int d = half * 256 + tid;
      float r_ = sigmoid_fast(gis[tid] + ghs[tid]);
      float z_ = sigmoid_fast(gis[256 + tid] + ghs[256 + tid]);
      float n_ = tanh_fast(gis[512 + tid] + r_ * ghs[512 + tid]);
      float hnew = (1.f - z_) * n_ + z_ * h_s[d];
      gstore(out_hT + (size_t)b * 512 + d, hnew);
    }
    pair_barrier(cnt, 2 * (++bc));
  }

  // ---- tail: out_d[:, T-1] from final h
  if (half == 0) {
    if (tid < 512) h_s[tid] = gload(out_hT + (size_t)b * 512 + tid);
    __syncthreads();
    if (tid < 192) {
      const int o = tid >> 6, ln = tid & 63;
      const float* wrow = W_out + (size_t)o * DD;
      float a = 0.f;
      for (int i = ln; i < DD; i += 64) a += h_s[i] * wrow[i];
#pragma unroll
      for (int off = 32; off; off >>= 1) a += __shfl_xor(a, off);
      if (ln == 0)
        out_d[((size_t)b * TT + (TT - 1)) * OO + o] = a + b_out[o];
    }
  }
}

// ---------------------------------------------------------------------------
extern "C" void kernel_launch(void* const* d_in, const int* in_sizes, int n_in,
                              void* d_out, int out_size, void* d_ws, size_t ws_size,
                              hipStream_t stream) {
  const float* e_all  = (const float*)d_in[0];
  const float* e_last = (const float*)d_in[1];
  const float* target = (const float*)d_in[2];
  const float* Wa     = (const float*)d_in[3];
  const float* ba     = (const float*)d_in[4];
  const float* Ua     = (const float*)d_in[5];
  const float* bu     = (const float*)d_in[6];
  const float* Va_w   = (const float*)d_in[7];
  const float* W_ih   = (const float*)d_in[9];
  const float* b_ih   = (const float*)d_in[10];
  const float* W_hh   = (const float*)d_in[11];
  const float* b_hh   = (const float*)d_in[12];
  const float* W_out  = (const float*)d_in[13];
  const float* b_out  = (const float*)d_in[14];

  float* out      = (float*)d_out;
  float* out_d    = out;                         // [B,T,3]
  float* out_hT   = out + (size_t)BB * TT * OO;  // [1,B,D]  (live h, f32)
  float* out_attn = out_hT + (size_t)BB * DD;    // [B,T,S]

  // Workspace layout (138,446,848 B <= 139,479,040 B proven-safe):
  //   0           Uk2     67,108,864
  //   67,108,864  e_bf    67,108,864
  //   134,217,728 Wq2        524,288   [512 j][512 k] bf16 (row-major)
  //   134,742,016 WihR     1,572,864   [1536 col][512 k] bf16
  //   136,314,880 WhhR     1,572,864
  //   137,887,744 bq           2,048
  //   137,889,792 ctxp       524,288   [128][2][512] f32  } Ua_bf (prologue)
  //   138,414,080 bars        32,768   128 x 256 B        } aliases ctxp
  char* wsB = (char*)d_ws;
  unsigned short* Uk2   = (unsigned short*)wsB;
  unsigned short* e_bfp = (unsigned short*)(wsB + 67108864);
  unsigned short* Wq2   = (unsigned short*)(wsB + 134217728);
  unsigned short* WihR  = (unsigned short*)(wsB + 134742016);
  unsigned short* WhhR  = (unsigned short*)(wsB + 136314880);
  float* bq             = (float*)(wsB + 137887744);
  float* ctxp           = (float*)(wsB + 137889792);
  char* bars            = wsB + 138414080;
  unsigned short* Ua_bf = (unsigned short*)(wsB + 137889792);  // prologue alias

  prep_wq2<<<(DD * DD) / 256, 256, 0, stream>>>(Wa, Wq2);
  prep_wihr<<<(1536 * 512) / 256, 256, 0, stream>>>(W_ih, WihR);
  prep_whhr<<<(1536 * 512) / 256, 256, 0, stream>>>(W_hh, WhhR);
  prep_bq<<<2, 256, 0, stream>>>(ba, bq);
  conv_bf<<<(BB * SS * DD) / (8 * 256), 256, 0, stream>>>(e_all, e_bfp);
  conv_bf<<<(DD * DD) / (8 * 256), 256, 0, stream>>>(Ua, Ua_bf);
  gemm_uk_mfma<<<dim3(DD / 128, (BB * SS) / 128), 256, 0, stream>>>(
      e_bfp, Ua_bf, bu, Uk2);

  hipMemsetAsync(bars, 0, 128 * 256, stream);

  decode_pairs<<<2 * BB, 1024, 0, stream>>>(
      Uk2, e_bfp, Wq2, WihR, WhhR, bq, W_ih, b_ih, b_hh, e_last, target,
      Va_w, W_out, b_out, ctxp, bars, out_d, out_hT, out_attn);
}

// Round 9
// 4677.972 us; speedup vs baseline: 1.4830x; 1.4830x over previous
//
#include <hip/hip_runtime.h>
#include <cstdint>

constexpr int BB = 128;   // batch
constexpr int SS = 512;   // source length
constexpr int DD = 512;   // hidden dim
constexpr int TT = 64;    // decode steps
constexpr int OO = 3;     // output dim

constexpr float C2LE = 2.8853900817779268f;  // 2*log2(e)

typedef __attribute__((ext_vector_type(8))) short bf16x8;
typedef __attribute__((ext_vector_type(4))) float f32x4;

__device__ __forceinline__ float tanh_fast(float x) {
  float e = __expf(2.0f * x);
  return 1.0f - 2.0f / (e + 1.0f);
}
__device__ __forceinline__ float sigmoid_fast(float x) {
  return 1.0f / (1.0f + __expf(-x));
}
__device__ __forceinline__ unsigned short f2bf(float f) {
  uint32_t u = __float_as_uint(f);
  uint32_t r = (u + 0x7FFFu + ((u >> 16) & 1u)) >> 16;  // RNE
  return (unsigned short)r;
}
__device__ __forceinline__ float bf2f(unsigned short h) {
  return __uint_as_float((uint32_t)h << 16);
}
__device__ __forceinline__ float fexp2(float x) {
#if __has_builtin(__builtin_amdgcn_exp2f)
  return __builtin_amdgcn_exp2f(x);
#else
  return exp2f(x);
#endif
}
__device__ __forceinline__ float frcp(float x) {
#if __has_builtin(__builtin_amdgcn_rcpf)
  return __builtin_amdgcn_rcpf(x);
#else
  return 1.0f / x;
#endif
}

// LLC-coherent (agent-scope) accessors for cross-block exchange.
__device__ __forceinline__ void gstore(float* p, float v) {
  __hip_atomic_store(p, v, __ATOMIC_RELAXED, __HIP_MEMORY_SCOPE_AGENT);
}
__device__ __forceinline__ float gload(const float* p) {
  return __hip_atomic_load(p, __ATOMIC_RELAXED, __HIP_MEMORY_SCOPE_AGENT);
}

// Fence-free group barrier (R6-proven mechanism, 4-way): drain own stores
// (vmcnt), then one lane arrive+spin on this group's private 256-B line.
__device__ __forceinline__ void grp_barrier(unsigned int* cnt,
                                            unsigned int target) {
  asm volatile("s_waitcnt vmcnt(0)" ::: "memory");
  __syncthreads();
  if (threadIdx.x == 0) {
    __hip_atomic_fetch_add(cnt, 1u, __ATOMIC_RELAXED, __HIP_MEMORY_SCOPE_AGENT);
    while (__hip_atomic_load(cnt, __ATOMIC_RELAXED,
                             __HIP_MEMORY_SCOPE_AGENT) < target)
      __builtin_amdgcn_s_sleep(2);
  }
  __syncthreads();
}

// ---------------------------------------------------------------------------
// MFMA bf16 GEMM producing d-quarter-transposed Uk:
//   Ukq[b][dq][d'][s] = bf16( C2LE * (e_bf @ Ua_bf^T + bu) ), d = dq*128+d'
// 8-B packed stores (4 consecutive s per lane).
// ---------------------------------------------------------------------------
__global__ __launch_bounds__(256) void gemm_uk_mfma(
    const unsigned short* __restrict__ A, const unsigned short* __restrict__ Bw,
    const float* __restrict__ bias, unsigned short* __restrict__ Ukq) {
  __shared__ unsigned short Asb[128 * 40];
  __shared__ unsigned short Bsb[128 * 40];
  const int tid = threadIdx.x;
  const int m0 = blockIdx.y * 128, n0 = blockIdx.x * 128;
  const int w = tid >> 6, l = tid & 63;
  const int wr = w >> 1, wc = w & 1;
  const int lm = l & 15, kg = l >> 4;

  f32x4 acc[4][4] = {};

  for (int kc = 0; kc < 512; kc += 32) {
    uint4 av[2], bv[2];
#pragma unroll
    for (int p = 0; p < 2; ++p) {
      int u = tid + p * 256;
      int r = u >> 2, ko = (u & 3) * 8;
      av[p] = *(const uint4*)(A + (size_t)(m0 + r) * 512 + kc + ko);
      bv[p] = *(const uint4*)(Bw + (size_t)(n0 + r) * 512 + kc + ko);
    }
    __syncthreads();
#pragma unroll
    for (int p = 0; p < 2; ++p) {
      int u = tid + p * 256;
      int r = u >> 2, ko = (u & 3) * 8;
      *(uint4*)&Asb[r * 40 + ko] = av[p];
      *(uint4*)&Bsb[r * 40 + ko] = bv[p];
    }
    __syncthreads();
    bf16x8 af[4], bfr[4];
#pragma unroll
    for (int i = 0; i < 4; ++i) {
      af[i]  = *(const bf16x8*)&Asb[(wr * 64 + i * 16 + lm) * 40 + kg * 8];
      bfr[i] = *(const bf16x8*)&Bsb[(wc * 64 + i * 16 + lm) * 40 + kg * 8];
    }
#pragma unroll
    for (int i = 0; i < 4; ++i)
#pragma unroll
      for (int j = 0; j < 4; ++j)
        acc[i][j] = __builtin_amdgcn_mfma_f32_16x16x32_bf16(af[i], bfr[j],
                                                            acc[i][j], 0, 0, 0);
  }

  const int row_base = m0 + wr * 64;
  const int col_base = n0 + wc * 64;
#pragma unroll
  for (int j = 0; j < 4; ++j) {
    const int col = col_base + j * 16 + lm;
    const int dqi = col >> 7, dpi = col & 127;
    const float buv = bias[col];
#pragma unroll
    for (int i = 0; i < 4; ++i) {
      const int r0 = row_base + i * 16 + kg * 4;  // 4-aligned, no 512-crossing
      const int bb = r0 >> 9, ss = r0 & 511;
      ushort4 pk;
      pk.x = f2bf(C2LE * (acc[i][j][0] + buv));
      pk.y = f2bf(C2LE * (acc[i][j][1] + buv));
      pk.z = f2bf(C2LE * (acc[i][j][2] + buv));
      pk.w = f2bf(C2LE * (acc[i][j][3] + buv));
      *(ushort4*)&Ukq[(((size_t)bb * 4 + dqi) * 128 + dpi) * 512 + ss] = pk;
    }
  }
}

// fp32 -> bf16, 8 elems/thread
__global__ __launch_bounds__(256) void conv_bf(const float* __restrict__ in,
                                               unsigned short* __restrict__ outp) {
  size_t idx = ((size_t)blockIdx.x * 256 + threadIdx.x) * 8;
  const float4* p = (const float4*)(in + idx);
  float4 a = p[0], b = p[1];
  uint4 r;
  r.x = f2bf(a.x) | ((uint32_t)f2bf(a.y) << 16);
  r.y = f2bf(a.z) | ((uint32_t)f2bf(a.w) << 16);
  r.z = f2bf(b.x) | ((uint32_t)f2bf(b.y) << 16);
  r.w = f2bf(b.z) | ((uint32_t)f2bf(b.w) << 16);
  *(uint4*)(outp + idx) = r;
}

// Wq2t[k*512 + j] = bf16(C2LE * Wa[j][k])   (k-major: lane-per-column)
__global__ void prep_wq2t(const float* __restrict__ Wa,
                          unsigned short* __restrict__ Wq2t) {
  int idx = blockIdx.x * 256 + threadIdx.x;  // k*512 + j
  int k = idx >> 9, j = idx & 511;
  Wq2t[idx] = f2bf(C2LE * Wa[(size_t)j * DD + k]);
}

// WihT[k*1536 + col] = bf16(W_ih[col][k]), col = gate*512 + d  (k-major)
__global__ void prep_wihT(const float* __restrict__ W_ih,
                          unsigned short* __restrict__ WihT) {
  int idx = blockIdx.x * 256 + threadIdx.x;  // 512*1536
  int k = idx / 1536, col = idx % 1536;
  WihT[idx] = f2bf(W_ih[(size_t)col * (DD + OO) + k]);
}

// WhhT same, from W_hh (ld 512)
__global__ void prep_whhT(const float* __restrict__ Whh,
                          unsigned short* __restrict__ WhhT) {
  int idx = blockIdx.x * 256 + threadIdx.x;  // 512*1536
  int k = idx / 1536, col = idx % 1536;
  WhhT[idx] = f2bf(Whh[(size_t)col * DD + k]);
}

__global__ void prep_bq(const float* __restrict__ ba, float* __restrict__ bq) {
  int j = blockIdx.x * 256 + threadIdx.x;  // 512
  bq[j] = C2LE * ba[j];
}

// ---------------------------------------------------------------------------
// Persistent quad decode: 256 blocks = 64 groups (2 batches each) x 4
// d-quarter slices; 1024 threads; whole T-loop. 3 fence-free 4-way barriers
// per step. All output-dim work (q2, scores-partials, ctx, gi/gh, GRU) is
// d-quarter-local; weights amortize over 2 batches.
// ---------------------------------------------------------------------------
__global__ __launch_bounds__(1024, 1) void decode_quads(
    const unsigned short* __restrict__ Ukq, const unsigned short* __restrict__ e_bf,
    const unsigned short* __restrict__ Wq2t, const unsigned short* __restrict__ WihT,
    const unsigned short* __restrict__ WhhT, const float* __restrict__ bq,
    const float* __restrict__ W_ih, const float* __restrict__ b_ih,
    const float* __restrict__ b_hh, const float* __restrict__ e_last,
    const float* __restrict__ target, const float* __restrict__ Va_w,
    const float* __restrict__ W_out, const float* __restrict__ b_out,
    float* __restrict__ scoresP, float* __restrict__ ctxg,
    float* __restrict__ op, char* __restrict__ bars,
    float* __restrict__ out_d, float* __restrict__ out_hT,
    float* __restrict__ out_attn) {
  const int blk = blockIdx.x, tid = threadIdx.x;
  const int g = blk >> 2, dq = blk & 3;
  const int b0 = g * 2;
  unsigned int* cnt = (unsigned int*)(bars + (size_t)g * 256);
  unsigned int bc = 0;

  __shared__ float h_s[2][512];
  __shared__ float q2_sl[2][128];
  __shared__ float pdq[3][2][128];
  __shared__ float va_sl[128];
  __shared__ float w_s[2][512];
  __shared__ float red_s[2][16];
  __shared__ float ctp[3][2][128];
  __shared__ float c_s[2][512];
  __shared__ f32x4 pd4[384];
  __shared__ float gi_s[2][384];
  __shared__ float gh_s[2][384];
  __shared__ float hn_s[2][128];
  __shared__ float x_s[2][3];

  // persistent preloads
  if (tid < 128) va_sl[tid] = Va_w[dq * 128 + tid];
  float wx0 = 0.f, wx1 = 0.f, wx2 = 0.f, bi_r = 0.f, bh_r = 0.f;
  if (tid < 384) {
    const int cc = tid & 127, gate = (tid >> 7) % 3;
    const int row = gate * 512 + dq * 128 + cc;
    const float* wp = W_ih + (size_t)row * (DD + OO) + DD;
    wx0 = wp[0]; wx1 = wp[1]; wx2 = wp[2];
    bi_r = b_ih[row]; bh_r = b_hh[row];
  }
  __syncthreads();

  for (int t = 0; t < TT; ++t) {
    // ---- P1a: load h (both b) + finalize out_d[t-1] (dq==0) --------------
    {
      const int bl = tid >> 9, d = tid & 511;
      h_s[bl][d] = (t == 0) ? e_last[(size_t)(b0 + bl) * 512 + d]
                            : gload(out_hT + (size_t)(b0 + bl) * 512 + d);
    }
    if (dq == 0 && t > 0 && tid >= 1018) {
      const int u = tid - 1018, bl = u / 3, o = u % 3;
      float s = 0.f;
#pragma unroll
      for (int q = 0; q < 4; ++q)
        s += gload(&op[(((size_t)(b0 + bl)) * 4 + q) * 3 + o]);
      out_d[((size_t)(b0 + bl) * TT + (t - 1)) * OO + o] = s + b_out[o];
    }
    __syncthreads();
    // ---- P1b: q2 slice GEMV (own 128 cols, both b) -----------------------
    {
      const int col = tid & 127, bl = (tid >> 7) & 1, kb = tid >> 8;
      const int colg = dq * 128 + col;
      float acc = 0.f;
#pragma unroll 8
      for (int k = kb * 128; k < kb * 128 + 128; ++k)
        acc += h_s[bl][k] * bf2f(Wq2t[(size_t)k * 512 + colg]);
      if (kb) pdq[kb - 1][bl][col] = acc;
      __syncthreads();
      if (kb == 0)
        q2_sl[bl][col] = acc + pdq[0][bl][col] + pdq[1][bl][col] +
                         pdq[2][bl][col] + bq[colg];
    }
    __syncthreads();
    // ---- P1c: scores partial over own d-quarter, all 512 s ---------------
    {
      const int bl = tid >> 9, s = tid & 511;
      const unsigned short* up =
          Ukq + (((size_t)(b0 + bl) * 4 + dq) * 128) * 512 + s;
      float acc = 0.f;
#pragma unroll 8
      for (int dpi = 0; dpi < 128; ++dpi) {
        unsigned short uv = __builtin_nontemporal_load(up + (size_t)dpi * 512);
        acc += va_sl[dpi] * frcp(1.f + fexp2(q2_sl[bl][dpi] + bf2f(uv)));
      }
      gstore(&scoresP[(((size_t)(b0 + bl)) * 4 + dq) * 512 + s], acc);
    }
    grp_barrier(cnt, 4 * (++bc));

    // ---- P2a: full softmax (redundant per block), attn-out own s-quarter -
    {
      const int bl = tid >> 9, s = tid & 511;
      const float* sp = &scoresP[((size_t)(b0 + bl)) * 4 * 512 + s];
      float y = -2.f * (gload(sp) + gload(sp + 512) + gload(sp + 1024) +
                        gload(sp + 1536));
      float m = y;
#pragma unroll
      for (int off = 32; off; off >>= 1) m = fmaxf(m, __shfl_xor(m, off));
      const int wv = (tid >> 6) & 7;
      if ((tid & 63) == 0) red_s[bl][wv] = m;
      __syncthreads();
      float gm = red_s[bl][0];
#pragma unroll
      for (int i = 1; i < 8; ++i) gm = fmaxf(gm, red_s[bl][i]);
      float e = __expf(y - gm);
      float sm = e;
#pragma unroll
      for (int off = 32; off; off >>= 1) sm += __shfl_xor(sm, off);
      if ((tid & 63) == 0) red_s[bl][8 + wv] = sm;
      __syncthreads();
      float Z = red_s[bl][8];
#pragma unroll
      for (int i = 1; i < 8; ++i) Z += red_s[bl][8 + i];
      float wgt = e * frcp(Z);
      w_s[bl][s] = wgt;
      if (s >= dq * 128 && s < dq * 128 + 128)
        __builtin_nontemporal_store(
            wgt, out_attn + ((size_t)(b0 + bl) * TT + t) * SS + s);
    }
    __syncthreads();
    // ---- P2b: ctx own d-quarter over all 512 s (4 s-chunks) --------------
    {
      const int ch = tid >> 8, bl = (tid >> 7) & 1, dpi = tid & 127;
      const unsigned short* eb =
          e_bf + ((size_t)(b0 + bl) * 512 + ch * 128) * 512 + dq * 128 + dpi;
      float acc = 0.f;
#pragma unroll 8
      for (int si = 0; si < 128; ++si) {
        unsigned short uv = __builtin_nontemporal_load(eb + (size_t)si * 512);
        acc += w_s[bl][ch * 128 + si] * bf2f(uv);
      }
      if (ch) ctp[ch - 1][bl][dpi] = acc;
      __syncthreads();
      if (ch == 0)
        gstore(&ctxg[(size_t)(b0 + bl) * 512 + dq * 128 + dpi],
               acc + ctp[0][bl][dpi] + ctp[1][bl][dpi] + ctp[2][bl][dpi]);
    }
    grp_barrier(cnt, 4 * (++bc));

    // ---- P3a: load full ctx (both b) + x values --------------------------
    {
      const int bl = tid >> 9, d = tid & 511;
      c_s[bl][d] = gload(&ctxg[(size_t)(b0 + bl) * 512 + d]);
    }
    if (tid >= 1016 && tid < 1022) {
      const int u = tid - 1016, bl = u / 3, o = u % 3;
      x_s[bl][o] =
          (t > 0) ? target[((size_t)(b0 + bl) * TT + (t - 1)) * OO + o] : 0.f;
    }
    __syncthreads();
    // ---- P3b: gi/gh GEMV own 384 cols, both b (k-split 2-way) ------------
    {
      float ai0 = 0.f, ai1 = 0.f, ah0 = 0.f, ah1 = 0.f;
      int cc = 0, gate = 0;
      if (tid < 768) {
        cc = tid & 127; gate = (tid >> 7) % 3;
        const int kb = tid / 384;
        const int colg = gate * 512 + dq * 128 + cc;
        const unsigned short* wi = WihT + colg;
        const unsigned short* wh = WhhT + colg;
#pragma unroll 8
        for (int k = kb * 256; k < kb * 256 + 256; ++k) {
          float wiv = bf2f(wi[(size_t)k * 1536]);
          float whv = bf2f(wh[(size_t)k * 1536]);
          ai0 += c_s[0][k] * wiv; ai1 += c_s[1][k] * wiv;
          ah0 += h_s[0][k] * whv; ah1 += h_s[1][k] * whv;
        }
        if (tid >= 384) {
          f32x4 v = {ai0, ai1, ah0, ah1};
          pd4[gate * 128 + cc] = v;
        }
      }
      __syncthreads();
      if (tid < 384) {
        f32x4 p = pd4[gate * 128 + cc];
        const int gc = gate * 128 + cc;
        gi_s[0][gc] = ai0 + p[0] + bi_r + x_s[0][0] * wx0 + x_s[0][1] * wx1 +
                      x_s[0][2] * wx2;
        gi_s[1][gc] = ai1 + p[1] + bi_r + x_s[1][0] * wx0 + x_s[1][1] * wx1 +
                      x_s[1][2] * wx2;
        gh_s[0][gc] = ah0 + p[2] + bh_r;
        gh_s[1][gc] = ah1 + p[3] + bh_r;
      }
    }
    __syncthreads();
    // ---- P3c: GRU pointwise (own 128 d, both b) --------------------------
    if (tid < 256) {
      const int bl = tid >> 7, cc = tid & 127;
      const int d = dq * 128 + cc;
      float r_ = sigmoid_fast(gi_s[bl][cc] + gh_s[bl][cc]);
      float z_ = sigmoid_fast(gi_s[bl][128 + cc] + gh_s[bl][128 + cc]);
      float n_ = tanh_fast(gi_s[bl][256 + cc] + r_ * gh_s[bl][256 + cc]);
      float hnew = (1.f - z_) * n_ + z_ * h_s[bl][d];
      gstore(out_hT + (size_t)(b0 + bl) * 512 + d, hnew);
      hn_s[bl][cc] = hnew;
    }
    __syncthreads();
    // ---- P3d: out-proj partials for own d-quarter ------------------------
    if (tid >= 256 && tid < 640) {
      const int u = tid - 256, grp = u >> 6, ln = u & 63;
      const int o = grp % 3, bl = grp / 3;
      const float* wrow = W_out + (size_t)o * DD + dq * 128;
      float acc = hn_s[bl][ln] * wrow[ln] + hn_s[bl][ln + 64] * wrow[ln + 64];
#pragma unroll
      for (int off = 32; off; off >>= 1) acc += __shfl_xor(acc, off);
      if (ln == 0)
        gstore(&op[(((size_t)(b0 + bl)) * 4 + dq) * 3 + o], acc);
    }
    grp_barrier(cnt, 4 * (++bc));
  }

  // ---- tail: out_d[:, T-1]
  if (dq == 0 && tid >= 1018) {
    const int u = tid - 1018, bl = u / 3, o = u % 3;
    float s = 0.f;
#pragma unroll
    for (int q = 0; q < 4; ++q)
      s += gload(&op[(((size_t)(b0 + bl)) * 4 + q) * 3 + o]);
    out_d[((size_t)(b0 + bl) * TT + (TT - 1)) * OO + o] = s + b_out[o];
  }
}

// ---------------------------------------------------------------------------
extern "C" void kernel_launch(void* const* d_in, const int* in_sizes, int n_in,
                              void* d_out, int out_size, void* d_ws, size_t ws_size,
                              hipStream_t stream) {
  const float* e_all  = (const float*)d_in[0];
  const float* e_last = (const float*)d_in[1];
  const float* target = (const float*)d_in[2];
  const float* Wa     = (const float*)d_in[3];
  const float* ba     = (const float*)d_in[4];
  const float* Ua     = (const float*)d_in[5];
  const float* bu     = (const float*)d_in[6];
  const float* Va_w   = (const float*)d_in[7];
  const float* W_ih   = (const float*)d_in[9];
  const float* b_ih   = (const float*)d_in[10];
  const float* W_hh   = (const float*)d_in[11];
  const float* b_hh   = (const float*)d_in[12];
  const float* W_out  = (const float*)d_in[13];
  const float* b_out  = (const float*)d_in[14];

  float* out      = (float*)d_out;
  float* out_d    = out;                         // [B,T,3]
  float* out_hT   = out + (size_t)BB * TT * OO;  // [1,B,D]  (live h, f32)
  float* out_attn = out_hT + (size_t)BB * DD;    // [B,T,S]

  // Workspace layout (139,223,040 B <= 139,479,040 B proven-safe):
  //   0           Ukq     67,108,864   [128 b][4 dq][128 d'][512 s] bf16
  //   67,108,864  e_bf    67,108,864
  //   134,217,728 Wq2t       524,288   [512 k][512 j] bf16 (k-major)
  //   134,742,016 WihT     1,572,864   [512 k][1536 col] bf16
  //   136,314,880 WhhT     1,572,864
  //   137,887,744 bq           2,048
  //   137,889,792 scoresP  1,048,576   [128 b][4 dq][512 s] f32  } Ua_bf alias
  //   138,938,368 ctxg       262,144   [128 b][512] f32
  //   139,200,512 op           6,144   [128 b][4 dq][3] f32
  //   139,206,656 bars        16,384   64 x 256 B
  char* wsB = (char*)d_ws;
  unsigned short* Ukq   = (unsigned short*)wsB;
  unsigned short* e_bfp = (unsigned short*)(wsB + 67108864);
  unsigned short* Wq2t  = (unsigned short*)(wsB + 134217728);
  unsigned short* WihT  = (unsigned short*)(wsB + 134742016);
  unsigned short* WhhT  = (unsigned short*)(wsB + 136314880);
  float* bq             = (float*)(wsB + 137887744);
  float* scoresP        = (float*)(wsB + 137889792);
  float* ctxg           = (float*)(wsB + 138938368);
  float* op             = (float*)(wsB + 139200512);
  char* bars            = wsB + 139206656;
  unsigned short* Ua_bf = (unsigned short*)(wsB + 137889792);  // prologue alias

  prep_wq2t<<<(DD * DD) / 256, 256, 0, stream>>>(Wa, Wq2t);
  prep_wihT<<<(512 * 1536) / 256, 256, 0, stream>>>(W_ih, WihT);
  prep_whhT<<<(512 * 1536) / 256, 256, 0, stream>>>(W_hh, WhhT);
  prep_bq<<<2, 256, 0, stream>>>(ba, bq);
  conv_bf<<<(BB * SS * DD) / (8 * 256), 256, 0, stream>>>(e_all, e_bfp);
  conv_bf<<<(DD * DD) / (8 * 256), 256, 0, stream>>>(Ua, Ua_bf);
  gemm_uk_mfma<<<dim3(DD / 128, (BB * SS) / 128), 256, 0, stream>>>(
      e_bfp, Ua_bf, bu, Ukq);

  hipMemsetAsync(bars, 0, 64 * 256, stream);

  decode_quads<<<256, 1024, 0, stream>>>(
      Ukq, e_bfp, Wq2t, WihT, WhhT, bq, W_ih, b_ih, b_hh, e_last, target,
      Va_w, W_out, b_out, scoresP, ctxg, op, bars, out_d, out_hT, out_attn);
}